// Round 11
// baseline (35122.058 us; speedup 1.0000x reference)
//
#include <hip/hip_runtime.h>

typedef __attribute__((ext_vector_type(4))) float f32x4;
typedef __attribute__((ext_vector_type(8))) short short8;
typedef __attribute__((ext_vector_type(2))) _Float16 half2v;
typedef unsigned int u32;
typedef unsigned short u16;
typedef unsigned long long u64;

#define T_SEQ 4096
#define HDIM  2048
#define GDIM  8192   // 4*H
#define INDIM 512
#define NBLK  256    // recurrence blocks
#define LINE_U64 16  // 128B line per producer in hpub

#if defined(__has_builtin)
#if __has_builtin(__builtin_amdgcn_fdot2)
#define HAS_FDOT2 1
#endif
#if __has_builtin(__builtin_amdgcn_exp2f)
#define EXP2F(x) __builtin_amdgcn_exp2f(x)   // v_exp_f32: 2^x, ~1 ulp
#endif
#endif
#ifndef HAS_FDOT2
#define HAS_FDOT2 0
#endif
#ifndef EXP2F
#define EXP2F(x) exp2f(x)
#endif

__device__ __forceinline__ u16 f2bf(float x) {
  u32 u = __float_as_uint(x);
  return (u16)((u + 0x7fffu + ((u >> 16) & 1u)) >> 16);  // RNE
}
__device__ __forceinline__ u16 f2h(float x) {
  _Float16 h = (_Float16)x;  // RNE
  return __builtin_bit_cast(unsigned short, h);
}
__device__ __forceinline__ float hlo(u32 u) {
  return (float)__builtin_bit_cast(_Float16, (unsigned short)(u & 0xffffu));
}
__device__ __forceinline__ float hhi(u32 u) {
  return (float)__builtin_bit_cast(_Float16, (unsigned short)(u >> 16));
}

// relaxed agent-scope accessors (single sc-bit op to coherence point, no
// invalidate/writeback). RULE (round-6): spin-poll addresses must be few per
// line; R10-proven scale ~256 req/line/sweep, this round ~1024 (watched).
__device__ __forceinline__ u64 aload64(const u64* p) {
  return __hip_atomic_load(p, __ATOMIC_RELAXED, __HIP_MEMORY_SCOPE_AGENT);
}
__device__ __forceinline__ void astore64(u64* p, u64 v) {
  __hip_atomic_store(p, v, __ATOMIC_RELAXED, __HIP_MEMORY_SCOPE_AGENT);
}
// tag check: both packed floats carry tg in their 2 mantissa LSBs
__device__ __forceinline__ bool tagok(u64 x, u32 tg) {
  return (((u32)x & 3u) == tg) && (((u32)(x >> 32) & 3u) == tg);
}

// ---------------- prep kernels ----------------
__global__ void k_zero_f32(float* __restrict__ p, int n) {
  int i = blockIdx.x * blockDim.x + threadIdx.x;
  int st = gridDim.x * blockDim.x;
  for (; i < n; i += st) p[i] = 0.f;
}

// hpub init: slot 0 = tagged zeros (tag(t=0) = ((0>>2)+1)&3 = 1 -> bits 1 per
// float, value ~1.4e-45 == 0 after f16 cast), slots 1..3 = raw zeros (tag 0,
// never matches any expected tag, which is always recomputed as (k+1)&3 with
// the +1 making pre-zero false-matches only possible when expected==0, i.e.
// occupant cycle positions that are always preceded by real writes).
__global__ void k_init_hpub(u64* __restrict__ a, u64* __restrict__ b) {
  int i = blockIdx.x * blockDim.x + threadIdx.x;  // 4*NBLK*LINE_U64 = 16384
  if (i < 4 * NBLK * LINE_U64) {
    u64 v = (i < NBLK * LINE_U64) ? 0x0000000100000001ULL : 0ULL;
    a[i] = v;
    b[i] = v;
  }
}

__global__ void k_bias_sum(const float* __restrict__ a, const float* __restrict__ b,
                           float* __restrict__ o, int n) {
  int i = blockIdx.x * blockDim.x + threadIdx.x;
  if (i < n) o[i] = a[i] + b[i];
}

__global__ void k_cvt_bf16(const float* __restrict__ in, u16* __restrict__ out, int n) {
  int i = blockIdx.x * blockDim.x + threadIdx.x;
  int st = gridDim.x * blockDim.x;
  for (; i < n; i += st) out[i] = f2bf(in[i]);
}

// Pre-pack W_hh (fp32 [8192][2048]) into per-block striped f16 layout (R6-proven).
__global__ __launch_bounds__(512) void k_prep_whh(const float* __restrict__ w,
                                                  uint4* __restrict__ out) {
  const int bid = blockIdx.x;
  const int tid = threadIdx.x;
#pragma unroll
  for (int s = 0; s < 16; ++s) {
    int slot = s * 512 + tid;
    int l = slot & 63, r3 = slot >> 6;
    int g = r3 & 3, q = (r3 >> 2) & 3, wv = r3 >> 4;
    int grow = q * HDIM + bid * 8 + wv;
    const float* src = w + (size_t)grow * HDIM + l * 32 + g * 8;
    uint4 o;
    o.x = (u32)f2h(src[0]) | ((u32)f2h(src[1]) << 16);
    o.y = (u32)f2h(src[2]) | ((u32)f2h(src[3]) << 16);
    o.z = (u32)f2h(src[4]) | ((u32)f2h(src[5]) << 16);
    o.w = (u32)f2h(src[6]) | ((u32)f2h(src[7]) << 16);
    out[((size_t)bid * 16 + s) * 512 + tid] = o;
  }
}

// ---------------- bf16 MFMA GEMM:  C[M,N] = A[M,K] * B[N,K]^T + bias[N] ----------------
template <bool AF32>
__global__ __launch_bounds__(256) void gemm_bt_bias(
    const void* __restrict__ Av, const u16* __restrict__ B,
    const float* __restrict__ bias, float* __restrict__ C,
    int M, int N, int K)
{
  __shared__ u16 As[128 * 64];
  __shared__ u16 Bs[128 * 64];
  const int tid = threadIdx.x;
  const int m0 = blockIdx.y * 128;
  const int n0 = blockIdx.x * 128;
  const int w = tid >> 6;
  const int lane = tid & 63;
  const int wm = (w >> 1) * 64, wn = (w & 1) * 64;
  const int lr = lane & 15, lk = lane >> 4;

  f32x4 acc[4][4];
  f32x4 zero = {0.f, 0.f, 0.f, 0.f};
#pragma unroll
  for (int i = 0; i < 4; ++i)
#pragma unroll
    for (int j = 0; j < 4; ++j) acc[i][j] = zero;

  const int r = tid >> 1;
  const int sbase = (tid & 1) * 4;

  for (int kt = 0; kt < K; kt += 64) {
    uint4 va[4], vb[4];
#pragma unroll
    for (int s = 0; s < 4; ++s) {
      if constexpr (AF32) {
        const float* ga = (const float*)Av + (size_t)(m0 + r) * K + kt + (sbase + s) * 8;
        float4 f0 = *reinterpret_cast<const float4*>(ga);
        float4 f1 = *reinterpret_cast<const float4*>(ga + 4);
        va[s].x = (u32)f2bf(f0.x) | ((u32)f2bf(f0.y) << 16);
        va[s].y = (u32)f2bf(f0.z) | ((u32)f2bf(f0.w) << 16);
        va[s].z = (u32)f2bf(f1.x) | ((u32)f2bf(f1.y) << 16);
        va[s].w = (u32)f2bf(f1.z) | ((u32)f2bf(f1.w) << 16);
      } else {
        const u16* ga = (const u16*)Av + (size_t)(m0 + r) * K + kt + (sbase + s) * 8;
        va[s] = *reinterpret_cast<const uint4*>(ga);
      }
      const u16* gb = B + (size_t)(n0 + r) * K + kt + (sbase + s) * 8;
      vb[s] = *reinterpret_cast<const uint4*>(gb);
    }
    __syncthreads();
#pragma unroll
    for (int s = 0; s < 4; ++s) {
      int ps = (sbase + s) ^ (r & 7);
      *reinterpret_cast<uint4*>(&As[r * 64 + ps * 8]) = va[s];
      *reinterpret_cast<uint4*>(&Bs[r * 64 + ps * 8]) = vb[s];
    }
    __syncthreads();
#pragma unroll
    for (int k32 = 0; k32 < 2; ++k32) {
      short8 af[4], bg[4];
#pragma unroll
      for (int i = 0; i < 4; ++i) {
        int arow = wm + i * 16 + lr;
        int aslot = (k32 * 4 + lk) ^ (arow & 7);
        af[i] = *reinterpret_cast<const short8*>(&As[arow * 64 + aslot * 8]);
        int brow = wn + i * 16 + lr;
        int bslot = (k32 * 4 + lk) ^ (brow & 7);
        bg[i] = *reinterpret_cast<const short8*>(&Bs[brow * 64 + bslot * 8]);
      }
#pragma unroll
      for (int i = 0; i < 4; ++i)
#pragma unroll
        for (int j = 0; j < 4; ++j)
          acc[i][j] = __builtin_amdgcn_mfma_f32_16x16x32_bf16(af[i], bg[j], acc[i][j], 0, 0, 0);
    }
  }

#pragma unroll
  for (int j = 0; j < 4; ++j) {
    int gcol = n0 + wn + j * 16 + lr;
    float bv = bias[gcol];
#pragma unroll
    for (int i = 0; i < 4; ++i) {
      int grow = m0 + wm + i * 16 + lk * 4;
#pragma unroll
      for (int rr = 0; rr < 4; ++rr)
        C[(size_t)(grow + rr) * N + gcol] = acc[i][j][rr] + bv;
    }
  }
}

// ---------------- persistent LSTM recurrence, single-message handoff ----------
// 256 blocks x 512 threads (8 waves). Weights f16 in LDS + pre-poll register
// prefetch (R8), fdot2 dot (R6), wave-parallel exp2 gates (R10).
// NEW: tag-in-mantissa h publishes. Producer (wave4 lanes 0-3, after barrier B)
// packs 8 h floats as 4 u64 {2 x f32, tag in 2 mantissa LSBs} on a private
// 128B line: hpub[slot t+1 & 3][bid]. Consumer: wave0 lane l polls its 4
// producers' 4 u64s each (done-mask, s_sleep backoff) -- detection DELIVERS
// the data -- then writes swizzled hT[t&1] (double-buffered), one barrier, dot.
// Tag(t) = ((t>>2)+1)&3: ring-slot occupants (4 steps apart) always differ;
// pre-zero (tag 0) never false-matches; slot 0 pre-init'd with tagged zeros.
// Max producer/consumer skew = 1 step (each step is a global rendezvous).
__global__ __launch_bounds__(512, 1)
__attribute__((amdgpu_waves_per_eu(2, 2)))
void lstm_rec(
    const float* __restrict__ gx,    // [T][8192] input contribution (+biases)
    const uint4* __restrict__ wp,    // pre-packed f16 weights [256][16][512]
    u64* __restrict__ hpub,          // [4][NBLK][LINE_U64] tagged h ring
    float* __restrict__ hist,        // [T+1][2048] plain h history, or nullptr
    int T)
{
  __shared__ uint4 wlds[16 * 512];   // 128 KiB f16 weights
  __shared__ float4 hT2[2][512];     // 2 x 8 KiB swizzled h rows (dbuf)
  __shared__ float h_out[8];
  const int tid = threadIdx.x;
  const int bid = blockIdx.x;
  const int wv = tid >> 6;  // wave -> h element bid*8+wv
  const int l = tid & 63;

  // stage weights once (coalesced)
#pragma unroll
  for (int s = 0; s < 16; ++s)
    wlds[s * 512 + tid] = wp[((size_t)bid * 16 + s) * 512 + tid];
  __syncthreads();  // B0: wlds complete before first prefetch

  float c = 0.f;  // cell state (all lanes of each wave, consistent)

  for (int t = 0; t < T; ++t) {
    // weight prefetch into registers (overlaps the poll; R2/R8 idiom)
    uint4 wr[16];
#pragma unroll
    for (int s = 0; s < 16; ++s) wr[s] = wlds[(wv * 16 + s) * 64 + l];
#pragma unroll
    for (int s = 0; s < 16; ++s)
      asm volatile("" : "+v"(wr[s].x), "+v"(wr[s].y), "+v"(wr[s].z), "+v"(wr[s].w));

    // gx prefetch (cached; independent of h[t])
    float gv = 0.f;
    if (l < 4) gv = gx[(size_t)t * GDIM + l * HDIM + bid * 8 + wv];

    // ---- wave0: poll-and-carry h[t], then stage to hT[t&1] ----
    if (wv == 0) {
      const u32 tg = (((u32)t >> 2) + 1) & 3u;
      const u64* base = hpub + (size_t)(t & 3) * (NBLK * LINE_U64);
      u64 d[16];
      u32 done = 0;
      while (done != 0xFu) {
#pragma unroll
        for (int pi = 0; pi < 4; ++pi) {
          if (done & (1u << pi)) continue;
          const u64* ln = base + (size_t)(l * 4 + pi) * LINE_U64;
          u64 x0 = aload64(ln + 0);
          u64 x1 = aload64(ln + 1);
          u64 x2 = aload64(ln + 2);
          u64 x3 = aload64(ln + 3);
          if (tagok(x0, tg) && tagok(x1, tg) && tagok(x2, tg) && tagok(x3, tg)) {
            d[pi * 4 + 0] = x0; d[pi * 4 + 1] = x1;
            d[pi * 4 + 2] = x2; d[pi * 4 + 3] = x3;
            done |= (1u << pi);
          }
        }
        if (done != 0xFu) __builtin_amdgcn_s_sleep(1);
      }
      // lane l carries h elements [32l .. 32l+32) = float4 indices v = 8l+j
#pragma unroll
      for (int j = 0; j < 8; ++j) {
        u64 a = d[2 * j], b = d[2 * j + 1];
        float4 hv;
        hv.x = __uint_as_float((u32)a);
        hv.y = __uint_as_float((u32)(a >> 32));
        hv.z = __uint_as_float((u32)b);
        hv.w = __uint_as_float((u32)(b >> 32));
        hT2[t & 1][j * 64 + (l ^ ((j * 9) & 63))] = hv;
      }
    }
    __syncthreads();  // A: h[t] staged (and prev iteration's publishes gathered)

    // dot: 8 hT reads + fdot2 against prefetched weights
    float a0 = 0.f, a1 = 0.f, a2 = 0.f, a3 = 0.f;
#pragma unroll
    for (int g = 0; g < 4; ++g) {
      const int G0 = g * 2, G1 = g * 2 + 1;
      float4 h0 = hT2[t & 1][G0 * 64 + (l ^ ((G0 * 9) & 63))];
      float4 h1 = hT2[t & 1][G1 * 64 + (l ^ ((G1 * 9) & 63))];
#if HAS_FDOT2
      half2v p0, p1, p2, p3;
      p0[0] = (_Float16)h0.x; p0[1] = (_Float16)h0.y;
      p1[0] = (_Float16)h0.z; p1[1] = (_Float16)h0.w;
      p2[0] = (_Float16)h1.x; p2[1] = (_Float16)h1.y;
      p3[0] = (_Float16)h1.z; p3[1] = (_Float16)h1.w;
#define FD2(wu, pp, acc) __builtin_amdgcn_fdot2(__builtin_bit_cast(half2v, (wu)), (pp), (acc), false)
      a0 = FD2(wr[0 + g].x, p0, FD2(wr[0 + g].y, p1, FD2(wr[0 + g].z, p2, FD2(wr[0 + g].w, p3, a0))));
      a1 = FD2(wr[4 + g].x, p0, FD2(wr[4 + g].y, p1, FD2(wr[4 + g].z, p2, FD2(wr[4 + g].w, p3, a1))));
      a2 = FD2(wr[8 + g].x, p0, FD2(wr[8 + g].y, p1, FD2(wr[8 + g].z, p2, FD2(wr[8 + g].w, p3, a2))));
      a3 = FD2(wr[12 + g].x, p0, FD2(wr[12 + g].y, p1, FD2(wr[12 + g].z, p2, FD2(wr[12 + g].w, p3, a3))));
#undef FD2
#else
      a0 += hlo(wr[0 + g].x) * h0.x + hhi(wr[0 + g].x) * h0.y + hlo(wr[0 + g].y) * h0.z + hhi(wr[0 + g].y) * h0.w +
            hlo(wr[0 + g].z) * h1.x + hhi(wr[0 + g].z) * h1.y + hlo(wr[0 + g].w) * h1.z + hhi(wr[0 + g].w) * h1.w;
      a1 += hlo(wr[4 + g].x) * h0.x + hhi(wr[4 + g].x) * h0.y + hlo(wr[4 + g].y) * h0.z + hhi(wr[4 + g].y) * h0.w +
            hlo(wr[4 + g].z) * h1.x + hhi(wr[4 + g].z) * h1.y + hlo(wr[4 + g].w) * h1.z + hhi(wr[4 + g].w) * h1.w;
      a2 += hlo(wr[8 + g].x) * h0.x + hhi(wr[8 + g].x) * h0.y + hlo(wr[8 + g].y) * h0.z + hhi(wr[8 + g].y) * h0.w +
            hlo(wr[8 + g].z) * h1.x + hhi(wr[8 + g].z) * h1.y + hlo(wr[8 + g].w) * h1.z + hhi(wr[8 + g].w) * h1.w;
      a3 += hlo(wr[12 + g].x) * h0.x + hhi(wr[12 + g].x) * h0.y + hlo(wr[12 + g].y) * h0.z + hhi(wr[12 + g].y) * h0.w +
            hlo(wr[12 + g].z) * h1.x + hhi(wr[12 + g].z) * h1.y + hlo(wr[12 + g].w) * h1.z + hhi(wr[12 + g].w) * h1.w;
#endif
    }
    // 64-lane butterfly
#pragma unroll
    for (int m = 32; m >= 1; m >>= 1) {
      a0 += __shfl_xor(a0, m);
      a1 += __shfl_xor(a1, m);
      a2 += __shfl_xor(a2, m);
      a3 += __shfl_xor(a3, m);
    }
    float g0 = __shfl(gv, 0), g1 = __shfl(gv, 1), g2 = __shfl(gv, 2), g3 = __shfl(gv, 3);

    // wave-parallel gates (R10): lanes 0-3 one activation each via v_exp_f32
    {
      const float L2E = 1.44269504f;
      float pre = (l & 2) ? ((l & 1) ? a3 + g3 : a2 + g2)
                          : ((l & 1) ? a1 + g1 : a0 + g0);
      float k = (l == 2) ? 2.f * L2E : -L2E;
      float e = EXP2F(k * pre);
      float act = (l == 2) ? (1.f - 2.f / (e + 1.f)) : (1.f / (1.f + e));
      float i_ = __shfl(act, 0);
      float f_ = __shfl(act, 1);
      float gg = __shfl(act, 2);
      float o_ = __shfl(act, 3);
      c = f_ * c + i_ * gg;
      float th = 1.f - 2.f / (EXP2F(2.f * L2E * c) + 1.f);
      if (l == 0) h_out[wv] = o_ * th;
    }
    __syncthreads();  // B: h_out complete

    // publisher: wave4 lanes 0-3 (off wave0's critical path) pack + publish
    if (wv == 4 && l < 4) {
      const u32 tg1 = (((u32)(t + 1) >> 2) + 1) & 3u;
      float ha = h_out[2 * l], hb = h_out[2 * l + 1];
      u32 ba = (__float_as_uint(ha) & ~3u) | tg1;
      u32 bb = (__float_as_uint(hb) & ~3u) | tg1;
      astore64(hpub + (size_t)((t + 1) & 3) * (NBLK * LINE_U64) + bid * LINE_U64 + l,
               (u64)ba | ((u64)bb << 32));
      if (hist) {  // layer-0 history for GEMM-1 (kernel-boundary flush covers it)
        float2 hv2; hv2.x = ha; hv2.y = hb;
        *reinterpret_cast<float2*>(hist + (size_t)(t + 1) * HDIM + bid * 8 + 2 * l) = hv2;
      }
    }
  }
}

// ---------------- heads: two 2048-dots (h read from tagged hpub slot) ----------------
__global__ void k_heads(const u64* __restrict__ hp, const float* __restrict__ wt,
                        const float* __restrict__ bt, const float* __restrict__ wf,
                        const float* __restrict__ bfp, float* __restrict__ out) {
  int tid = threadIdx.x;  // 256
  float st = 0.f, sf = 0.f;
  for (int i = tid; i < HDIM; i += 256) {
    u64 wpair = hp[(size_t)(i >> 3) * LINE_U64 + ((i & 7) >> 1)];
    float hv = (i & 1) ? __uint_as_float((u32)(wpair >> 32))
                       : __uint_as_float((u32)wpair);
    st += hv * wt[i];
    sf += hv * wf[i];
  }
#pragma unroll
  for (int m = 32; m >= 1; m >>= 1) {
    st += __shfl_xor(st, m, 64);
    sf += __shfl_xor(sf, m, 64);
  }
  __shared__ float ra[4], rb[4];
  if ((tid & 63) == 0) { ra[tid >> 6] = st; rb[tid >> 6] = sf; }
  __syncthreads();
  if (tid == 0) {
    out[0] = ra[0] + ra[1] + ra[2] + ra[3] + bt[0];
    out[1] = rb[0] + rb[1] + rb[2] + rb[3] + bfp[0];
  }
}

// ---------------- launch ----------------
extern "C" void kernel_launch(void* const* d_in, const int* in_sizes, int n_in,
                              void* d_out, int out_size, void* d_ws, size_t ws_size,
                              hipStream_t stream) {
  const float* x     = (const float*)d_in[0];
  const float* w_ih0 = (const float*)d_in[1];
  const float* w_hh0 = (const float*)d_in[2];
  const float* b_ih0 = (const float*)d_in[3];
  const float* b_hh0 = (const float*)d_in[4];
  const float* w_ih1 = (const float*)d_in[5];
  const float* w_hh1 = (const float*)d_in[6];
  const float* b_ih1 = (const float*)d_in[7];
  const float* b_hh1 = (const float*)d_in[8];
  const float* w_t   = (const float*)d_in[9];
  const float* b_t   = (const float*)d_in[10];
  const float* w_f   = (const float*)d_in[11];
  const float* b_f   = (const float*)d_in[12];

  // workspace layout (bytes), total ~236.4 MiB (known-good budget)
  char* p = (char*)d_ws;
  float* gx    = (float*)(p);                 // 134,217,728
  float* hs0f  = (float*)(p + 134217728);     // 4097*2048*4 = 33,562,624
  u16*   xb    = (u16*)  (p + 167780352);     // 4,194,304
  u16*   wb0   = (u16*)  (p + 171974656);     // 8,388,608
  u16*   wb1   = (u16*)  (p + 180363264);     // 33,554,432
  uint4* wprep = (uint4*)(p + 213917696);     // 33,554,432 (reused per layer)
  u64*   hpub0 = (u64*)  (p + 247472128);     // 4*256*128 = 131,072
  u64*   hpub1 = (u64*)  (p + 247603200);     // 131,072
  float* bias0 = (float*)(p + 247734272);     // 32,768
  float* bias1 = (float*)(p + 247767040);     // 32,768

  // init (re-run every launch => deterministic graph replay)
  k_zero_f32<<<8, 256, 0, stream>>>(hs0f, HDIM);   // history row 0 (unused by GEMM)
  k_init_hpub<<<64, 256, 0, stream>>>(hpub0, hpub1);
  k_bias_sum<<<GDIM / 256, 256, 0, stream>>>(b_ih0, b_hh0, bias0, GDIM);
  k_bias_sum<<<GDIM / 256, 256, 0, stream>>>(b_ih1, b_hh1, bias1, GDIM);
  k_cvt_bf16<<<1024, 256, 0, stream>>>(x, xb, T_SEQ * INDIM);
  k_cvt_bf16<<<1024, 256, 0, stream>>>(w_ih0, wb0, GDIM * INDIM);
  k_cvt_bf16<<<2048, 256, 0, stream>>>(w_ih1, wb1, GDIM * HDIM);

  // layer 0
  k_prep_whh<<<NBLK, 512, 0, stream>>>(w_hh0, wprep);
  gemm_bt_bias<false><<<dim3(GDIM / 128, T_SEQ / 128), 256, 0, stream>>>(
      xb, wb0, bias0, gx, T_SEQ, GDIM, INDIM);
  lstm_rec<<<NBLK, 512, 0, stream>>>(gx, wprep, hpub0, hs0f, T_SEQ);

  // layer 1 (A = hs0 fp32 rows 1..T, converted in GEMM staging)
  gemm_bt_bias<true><<<dim3(GDIM / 128, T_SEQ / 128), 256, 0, stream>>>(
      hs0f + HDIM, wb1, bias1, gx, T_SEQ, GDIM, HDIM);
  k_prep_whh<<<NBLK, 512, 0, stream>>>(w_hh1, wprep);
  lstm_rec<<<NBLK, 512, 0, stream>>>(gx, wprep, hpub1, (float*)nullptr, T_SEQ);

  // heads on h1[T] (ring slot T&3 == 0)
  k_heads<<<1, 256, 0, stream>>>(hpub1 + (size_t)(T_SEQ & 3) * (NBLK * LINE_U64),
                                 w_t, b_t, w_f, b_f, (float*)d_out);
}